// Round 1
// baseline (386.656 us; speedup 1.0000x reference)
//
#include <hip/hip_runtime.h>
#include <math.h>

#define D 128

typedef __bf16 v8bf __attribute__((ext_vector_type(8)));
typedef float v4f __attribute__((ext_vector_type(4)));

__device__ inline v8bf load_cvt8(const float* __restrict__ p) {
  const float4* p4 = (const float4*)p;
  float4 a = p4[0], b = p4[1];
  v8bf r;
  r[0] = (__bf16)a.x; r[1] = (__bf16)a.y; r[2] = (__bf16)a.z; r[3] = (__bf16)a.w;
  r[4] = (__bf16)b.x; r[5] = (__bf16)b.y; r[6] = (__bf16)b.z; r[7] = (__bf16)b.w;
  return r;
}

// Y[row][e] = (X[row][:] @ W[e][:] + bias[e]) * alpha, bf16 out, row-major.
// Block: 256 thr = 4 waves, each wave 16 rows x 128 cols.
__global__ __launch_bounds__(256) void proj_rowmajor(
    const float* __restrict__ X, const float* __restrict__ W,
    const float* __restrict__ bias, __bf16* __restrict__ Y, float alpha)
{
  const int w = threadIdx.x >> 6, l = threadIdx.x & 63;
  const int l16 = l & 15, l4 = l >> 4;
  const size_t rbase = (size_t)blockIdx.x * 64 + w * 16;

  v4f acc[8];
  #pragma unroll
  for (int ct = 0; ct < 8; ++ct) acc[ct] = (v4f){0.f, 0.f, 0.f, 0.f};

  #pragma unroll
  for (int kk = 0; kk < 4; ++kk) {
    v8bf a = load_cvt8(X + (rbase + l16) * D + kk * 32 + l4 * 8);
    #pragma unroll
    for (int ct = 0; ct < 8; ++ct) {
      v8bf bw = load_cvt8(W + (size_t)(ct * 16 + l16) * D + kk * 32 + l4 * 8);
      acc[ct] = __builtin_amdgcn_mfma_f32_16x16x32_bf16(a, bw, acc[ct], 0, 0, 0);
    }
  }
  #pragma unroll
  for (int ct = 0; ct < 8; ++ct) {
    float bv = bias[ct * 16 + l16];
    #pragma unroll
    for (int r = 0; r < 4; ++r) {
      float y = (acc[ct][r] + bv) * alpha;
      Y[(rbase + l4 * 4 + r) * D + ct * 16 + l16] = (__bf16)y;
    }
  }
}

// VT[b][e][n] = X[b][n][:] @ W[e][:] + bias[e]  (v projection, transposed store)
// Swapped operands: A = W (e x k), B = X^T (k x n). Block covers 128 e x 64 n.
__global__ __launch_bounds__(256) void proj_vT(
    const float* __restrict__ X, const float* __restrict__ W,
    const float* __restrict__ bias, __bf16* __restrict__ VT, int Nk)
{
  const int b = blockIdx.y;
  const float* Xb = X + (size_t)b * Nk * D;
  __bf16* VTb = VT + (size_t)b * D * Nk;
  const int w = threadIdx.x >> 6, l = threadIdx.x & 63;
  const int l16 = l & 15, l4 = l >> 4;
  const int ebase = w * 32;               // 2 row-tiles of e per wave
  const int nbase = blockIdx.x * 64;      // 4 col-tiles of n per block

  v4f acc[2][4];
  #pragma unroll
  for (int rt = 0; rt < 2; ++rt)
    #pragma unroll
    for (int ct = 0; ct < 4; ++ct) acc[rt][ct] = (v4f){0.f, 0.f, 0.f, 0.f};

  #pragma unroll
  for (int kk = 0; kk < 4; ++kk) {
    v8bf aw0 = load_cvt8(W + (size_t)(ebase + l16) * D + kk * 32 + l4 * 8);
    v8bf aw1 = load_cvt8(W + (size_t)(ebase + 16 + l16) * D + kk * 32 + l4 * 8);
    #pragma unroll
    for (int ct = 0; ct < 4; ++ct) {
      v8bf bx = load_cvt8(Xb + (size_t)(nbase + ct * 16 + l16) * D + kk * 32 + l4 * 8);
      acc[0][ct] = __builtin_amdgcn_mfma_f32_16x16x32_bf16(aw0, bx, acc[0][ct], 0, 0, 0);
      acc[1][ct] = __builtin_amdgcn_mfma_f32_16x16x32_bf16(aw1, bx, acc[1][ct], 0, 0, 0);
    }
  }
  #pragma unroll
  for (int rt = 0; rt < 2; ++rt) {
    const int e0 = ebase + rt * 16 + l4 * 4;
    #pragma unroll
    for (int r = 0; r < 4; ++r) {
      float bv = bias[e0 + r];
      #pragma unroll
      for (int ct = 0; ct < 4; ++ct)
        VTb[(size_t)(e0 + r) * Nk + nbase + ct * 16 + l16] = (__bf16)(acc[rt][ct][r] + bv);
    }
  }
}

// Flash attention: q pre-scaled by log2e/sqrt(D); K row-major bf16; V transposed bf16.
// Block: 4 waves x 16 q-rows. KV tile = 64.
__global__ __launch_bounds__(256) void attn_fwd(
    const __bf16* __restrict__ Qb, const __bf16* __restrict__ Kb,
    const __bf16* __restrict__ VTb, float* __restrict__ Out, int Nq, int Nk)
{
  const int b = blockIdx.y;
  const int w = threadIdx.x >> 6, l = threadIdx.x & 63;
  const int l16 = l & 15, l4 = l >> 4;
  const int qbase = blockIdx.x * 64 + w * 16;

  const __bf16* q = Qb + ((size_t)b * Nq + qbase) * D;
  const __bf16* kp = Kb + (size_t)b * Nk * D;
  const __bf16* vt = VTb + (size_t)b * D * Nk;

  __shared__ __align__(16) __bf16 p_lds[4][16][72];  // pad 72: 2-way alias only

  v8bf aq[4];
  #pragma unroll
  for (int kk = 0; kk < 4; ++kk)
    aq[kk] = *(const v8bf*)(q + l16 * D + kk * 32 + l4 * 8);

  v4f accO[8];
  #pragma unroll
  for (int ct = 0; ct < 8; ++ct) accO[ct] = (v4f){0.f, 0.f, 0.f, 0.f};
  float m[4], lsum[4];
  #pragma unroll
  for (int r = 0; r < 4; ++r) { m[r] = -1e30f; lsum[r] = 0.f; }

  for (int kv0 = 0; kv0 < Nk; kv0 += 64) {
    // S = q @ k^T  (16 x 64), 4 col-tiles
    v4f s[4];
    #pragma unroll
    for (int ct = 0; ct < 4; ++ct) s[ct] = (v4f){0.f, 0.f, 0.f, 0.f};
    #pragma unroll
    for (int ct = 0; ct < 4; ++ct) {
      const __bf16* krow = kp + (size_t)(kv0 + ct * 16 + l16) * D + l4 * 8;
      #pragma unroll
      for (int kk = 0; kk < 4; ++kk) {
        v8bf bk = *(const v8bf*)(krow + kk * 32);
        s[ct] = __builtin_amdgcn_mfma_f32_16x16x32_bf16(aq[kk], bk, s[ct], 0, 0, 0);
      }
    }
    // online softmax (scores already in log2 domain)
    float scale[4];
    #pragma unroll
    for (int r = 0; r < 4; ++r) {
      float mx = fmaxf(fmaxf(s[0][r], s[1][r]), fmaxf(s[2][r], s[3][r]));
      #pragma unroll
      for (int off = 8; off; off >>= 1) mx = fmaxf(mx, __shfl_xor(mx, off, 64));
      float mn = fmaxf(m[r], mx);
      scale[r] = exp2f(m[r] - mn);
      m[r] = mn;
      float rs = 0.f;
      #pragma unroll
      for (int ct = 0; ct < 4; ++ct) {
        float p = exp2f(s[ct][r] - mn);
        s[ct][r] = p;
        rs += p;
      }
      lsum[r] = lsum[r] * scale[r] + rs;  // per-lane partial; reduced at end
    }
    #pragma unroll
    for (int ct = 0; ct < 8; ++ct)
      #pragma unroll
      for (int r = 0; r < 4; ++r) accO[ct][r] *= scale[r];

    // D-layout -> A-layout transpose of P through LDS (per-wave, no barrier)
    #pragma unroll
    for (int ct = 0; ct < 4; ++ct)
      #pragma unroll
      for (int r = 0; r < 4; ++r)
        p_lds[w][l4 * 4 + r][ct * 16 + l16] = (__bf16)s[ct][r];

    // O += P @ V   (K-dim = keys, B = vT rows: contiguous)
    #pragma unroll
    for (int ks = 0; ks < 2; ++ks) {
      v8bf ap = *(const v8bf*)(&p_lds[w][l16][ks * 32 + l4 * 8]);
      #pragma unroll
      for (int ct = 0; ct < 8; ++ct) {
        v8bf bv = *(const v8bf*)(vt + (size_t)(ct * 16 + l16) * Nk + kv0 + ks * 32 + l4 * 8);
        accO[ct] = __builtin_amdgcn_mfma_f32_16x16x32_bf16(ap, bv, accO[ct], 0, 0, 0);
      }
    }
  }

  #pragma unroll
  for (int r = 0; r < 4; ++r) {
    float t = lsum[r];
    #pragma unroll
    for (int off = 8; off; off >>= 1) t += __shfl_xor(t, off, 64);
    lsum[r] = 1.f / t;
  }
  #pragma unroll
  for (int ct = 0; ct < 8; ++ct)
    #pragma unroll
    for (int r = 0; r < 4; ++r)
      Out[((size_t)b * Nq + qbase + l4 * 4 + r) * D + ct * 16 + l16] =
          accO[ct][r] * lsum[r];
}

extern "C" void kernel_launch(void* const* d_in, const int* in_sizes, int n_in,
                              void* d_out, int out_size, void* d_ws, size_t ws_size,
                              hipStream_t stream) {
  const float* Q  = (const float*)d_in[0];
  const float* K  = (const float*)d_in[1];
  const float* V  = (const float*)d_in[2];
  const float* Wq = (const float*)d_in[3];
  const float* bq = (const float*)d_in[4];
  const float* Wk = (const float*)d_in[5];
  const float* bk = (const float*)d_in[6];
  const float* Wv = (const float*)d_in[7];
  const float* bv = (const float*)d_in[8];
  float* out = (float*)d_out;

  const int B = 4, Nq = 4096, Nk = 4096;
  const size_t nElems = (size_t)B * Nq * D;

  __bf16* qbf  = (__bf16*)d_ws;
  __bf16* kbf  = qbf + nElems;
  __bf16* vtbf = kbf + nElems;

  const float alpha = 1.4426950408889634f / sqrtf((float)D);  // log2(e)/sqrt(D)

  proj_rowmajor<<<dim3(B * Nq / 64), 256, 0, stream>>>(Q, Wq, bq, qbf, alpha);
  proj_rowmajor<<<dim3(B * Nk / 64), 256, 0, stream>>>(K, Wk, bk, kbf, 1.0f);
  proj_vT<<<dim3(Nk / 64, B), 256, 0, stream>>>(V, Wv, bv, vtbf, Nk);
  attn_fwd<<<dim3(Nq / 64, B), 256, 0, stream>>>(qbf, kbf, vtbf, out, Nq, Nk);
}